// Round 6
// baseline (24.800 us; speedup 1.0000x reference)
//
#include <hip/hip_runtime.h>
#include <hip/hip_fp16.h>

#define GH 16
#define GW 16
#define GD 8
#define GC 12
#define H 1024
#define W 1024
#define NB 2

#define ROWS 2                    // rows per block
#define TPB 256                   // 4 px/thread -> one row per iteration

// LDS slab: i-pre-reduced grid, fp16, k-PAIR records.
// gI[gj][r][0..23]: halfs [0..11] = row gk=r ch 0..11, halfs [12..23] = row
// gk=r+1 ch 0..11, r in [0,6]. Pair record 48 B, 16B-aligned; gj stride 176
// halfs (352 B) rotates banks across gj-groups.
#define GPR 24
#define NPAIR (GD - 1)
#define GJS_H (NPAIR * GPR + 8)   // 176 halfs per gj
#define LDS_HALFS (GW * GJS_H)    // 2816 halfs = 5632 B

typedef float f4 __attribute__((ext_vector_type(4)));

// One 48B pair record (rows r,r+1 of one gj) -> 6 half2 accumulators.
__device__ inline void accum_rec(const __half* __restrict__ buf, int off,
                                 __half2 b0, __half2 b1, __half2* __restrict__ acc) {
  union U { uint4 u; __half2 h[4]; };
  const uint4* p = reinterpret_cast<const uint4*>(buf + off);
  U qa, qb, qc;
  qa.u = p[0]; qb.u = p[1]; qc.u = p[2];
  acc[0] = __hfma2(b0, qa.h[0], acc[0]);
  acc[1] = __hfma2(b0, qa.h[1], acc[1]);
  acc[2] = __hfma2(b0, qa.h[2], acc[2]);
  acc[3] = __hfma2(b0, qa.h[3], acc[3]);
  acc[4] = __hfma2(b0, qb.h[0], acc[4]);
  acc[5] = __hfma2(b0, qb.h[1], acc[5]);
  acc[0] = __hfma2(b1, qb.h[2], acc[0]);
  acc[1] = __hfma2(b1, qb.h[3], acc[1]);
  acc[2] = __hfma2(b1, qc.h[0], acc[2]);
  acc[3] = __hfma2(b1, qc.h[1], acc[3]);
  acc[4] = __hfma2(b1, qc.h[2], acc[4]);
  acc[5] = __hfma2(b1, qc.h[3], acc[5]);
}

__device__ inline void i_weights(int i, float& wi0, float& wi1, int& gi0c, int& gi1c) {
  float fi  = (i + 0.5f) * (1.0f / 64.0f) - 0.5f;
  float fif = floorf(fi);
  int   gi0 = (int)fif;
  float ti  = fi - fif;
  wi0 = 1.0f - ti; wi1 = ti;
  gi0c = gi0 < 0 ? 0 : gi0;
  gi1c = (gi0 + 1 > GH - 1) ? GH - 1 : gi0 + 1;
}

// Per-row staging: thread covers slots {tid, tid+256} of 384 (c,gk,gj-quad) slots.
struct Stage {
  float4 v0[2], v1[2];
  float wi0, wi1;
};

__device__ inline void stage_load(const float* __restrict__ gb, int tid, int i,
                                  Stage& st) {
  int gi0c, gi1c;
  i_weights(i, st.wi0, st.wi1, gi0c, gi1c);
#pragma unroll
  for (int q = 0; q < 2; ++q) {
    int s = tid + q * TPB;
    if (s < GC * GD * (GW / 4)) {
      const float* rowbase = gb + ((s >> 2) << 8);   // (c*8+gk)*256
      int gq = s & 3;
      st.v0[q] = *reinterpret_cast<const float4*>(rowbase + gi0c * GW + gq * 4);
      st.v1[q] = *reinterpret_cast<const float4*>(rowbase + gi1c * GW + gq * 4);
    }
  }
}

__device__ inline void stage_write(__half* __restrict__ buf, int tid, const Stage& st) {
#pragma unroll
  for (int q = 0; q < 2; ++q) {
    int s = tid + q * TPB;
    if (s < GC * GD * (GW / 4)) {
      int gq = s & 3;
      int ck = s >> 2;
      int gk = ck & 7;
      int c  = ck >> 3;
      float vals[4] = {st.wi0 * st.v0[q].x + st.wi1 * st.v1[q].x,
                       st.wi0 * st.v0[q].y + st.wi1 * st.v1[q].y,
                       st.wi0 * st.v0[q].z + st.wi1 * st.v1[q].z,
                       st.wi0 * st.v0[q].w + st.wi1 * st.v1[q].w};
#pragma unroll
      for (int m = 0; m < 4; ++m) {
        __half hv = __float2half(vals[m]);
        int base = (gq * 4 + m) * GJS_H;
        if (gk < GD - 1) buf[base + gk * GPR + c] = hv;            // row-low of pair gk
        if (gk > 0)      buf[base + (gk - 1) * GPR + 12 + c] = hv; // row-high of pair gk-1
      }
    }
  }
}

__global__ __launch_bounds__(TPB, 4) void slice_pipe_k(const float* __restrict__ grid,
                                                       const float* __restrict__ guide,
                                                       float* __restrict__ out) {
  __shared__ __half gI[2][LDS_HALFS];

  const int tid = threadIdx.x;
  const int r0  = blockIdx.x * ROWS;     // global row id base (= b*1024 + i0)
  const int b   = r0 >> 10;              // ROWS divides 1024: b uniform per block
  const int j0  = tid << 2;              // 4 px per thread

  const float* gb      = grid + (size_t)b * (GC * GD * GH * GW);
  const float* guide_b = guide + ((size_t)b << 20);

  // --- j cell (constant for this thread; quad never straddles a cell) ---
  float fj  = (j0 + 0.5f) * (1.0f / 64.0f) - 0.5f;
  float fjf = floorf(fj);
  int   gj0 = (int)fjf;
  float tj0 = fj - fjf;
  int gj0c = gj0 < 0 ? 0 : gj0;
  int gj1c = (gj0 + 1 > GW - 1) ? GW - 1 : gj0 + 1;
  const int rj0 = gj0c * GJS_H;
  const int rj1 = gj1c * GJS_H;

  // --- prologue: stage row r0 ---
  Stage st;
  stage_load(gb, tid, r0 & (H - 1), st);
  float4 g_cur = *reinterpret_cast<const float4*>(guide_b + ((r0 & (H - 1)) << 10) + j0);
  stage_write(gI[0], tid, st);
  __syncthreads();

  int cur = 0;
#pragma unroll
  for (int r = 0; r < ROWS; ++r) {
    const int i = (r0 + r) & (H - 1);
    const bool has_next = (r + 1 < ROWS);

    // (1) issue next row's loads early — latency hides under phase 2
    Stage nst;
    float4 g_nxt = {};
    if (has_next) {
      int i_n = (r0 + r + 1) & (H - 1);
      stage_load(gb, tid, i_n, nst);
      g_nxt = *reinterpret_cast<const float4*>(guide_b + (i_n << 10) + j0);
    }

    // (2) phase 2: 4 pixels from slab buffer `cur`
    const __half* buf = gI[cur];
    __half2 acc[4][6];
    const float gv[4] = {g_cur.x, g_cur.y, g_cur.z, g_cur.w};

#pragma unroll
    for (int p = 0; p < 4; ++p) {
      float tj  = tj0 + p * (1.0f / 64.0f);
      float wj0 = 1.0f - tj, wj1 = tj;

      // k weights: plain lerp (sqrt(tk^2+1e-8) == tk within 1e-4 for tk in [0,1)),
      // clamp folded into the pair weights (pair rr covers rows rr, rr+1).
      float fk  = gv[p] * (float)GD - 0.5f;
      float fkf = floorf(fk);
      int   gk0 = (int)fkf;                  // in [-1, 7]
      float tk  = fk - fkf;
      bool lo = gk0 < 0, hi = gk0 > GD - 2;
      int  rr = lo ? 0 : (hi ? GD - 2 : gk0);
      float a0 = lo ? 1.0f : (hi ? 0.0f : 1.0f - tk);
      float a1 = lo ? 0.0f : (hi ? 1.0f : tk);

      __half2 b00 = __float2half2_rn(wj0 * a0);
      __half2 b01 = __float2half2_rn(wj0 * a1);
      __half2 b10 = __float2half2_rn(wj1 * a0);
      __half2 b11 = __float2half2_rn(wj1 * a1);

      __half2* ap = acc[p];
#pragma unroll
      for (int t = 0; t < 6; ++t) ap[t] = __float2half2_rn(0.0f);

      int off = rr * GPR;
      accum_rec(buf, rj0 + off, b00, b01, ap);
      accum_rec(buf, rj1 + off, b10, b11, ap);
    }

    // stores: out[b][c][i][j0..j0+3], nontemporal float4 per channel
    float* ob = out + (((size_t)b * GC) << 20) + ((size_t)i << 10) + j0;
#pragma unroll
    for (int c2 = 0; c2 < 6; ++c2) {
      float2 f0 = __half22float2(acc[0][c2]);
      float2 f1 = __half22float2(acc[1][c2]);
      float2 f2 = __half22float2(acc[2][c2]);
      float2 f3 = __half22float2(acc[3][c2]);
      f4 vlo = {f0.x, f1.x, f2.x, f3.x};    // channel 2*c2
      f4 vhi = {f0.y, f1.y, f2.y, f3.y};    // channel 2*c2+1
      __builtin_nontemporal_store(vlo, reinterpret_cast<f4*>(ob + ((size_t)(2 * c2) << 20)));
      __builtin_nontemporal_store(vhi, reinterpret_cast<f4*>(ob + ((size_t)(2 * c2 + 1) << 20)));
    }

    // (3) write-late: next slab into the other buffer, then one barrier
    if (has_next) {
      stage_write(gI[cur ^ 1], tid, nst);
      g_cur = g_nxt;
      __syncthreads();
      cur ^= 1;
    }
  }
}

extern "C" void kernel_launch(void* const* d_in, const int* in_sizes, int n_in,
                              void* d_out, int out_size, void* d_ws, size_t ws_size,
                              hipStream_t stream) {
  const float* grid  = (const float*)d_in[0];   // (2,12,8,16,16) fp32
  const float* guide = (const float*)d_in[1];   // (2,1,1024,1024) fp32
  float* out = (float*)d_out;                   // (2,12,1024,1024) fp32

  const int nblocks = NB * H / ROWS;            // 1024 blocks = 4 per CU, resident
  slice_pipe_k<<<nblocks, TPB, 0, stream>>>(grid, guide, out);
}

// Round 7
// 23.996 us; speedup vs baseline: 1.0335x; 1.0335x over previous
//
#include <hip/hip_runtime.h>
#include <hip/hip_fp16.h>

#define GH 16
#define GW 16
#define GD 8
#define GC 12
#define H 1024
#define W 1024
#define NB 2

#define ROWS 4                    // rows per persistent block
#define TPB 512                   // threads per block (2 px/thread)

// Relaxed barrier: LDS consistency only. The default __syncthreads() emits
// s_waitcnt vmcnt(0) lgkmcnt(0) and would drain this iteration's output
// STORES at every barrier (m97-style stall). Staged global loads are consumed
// by ds_write before the barrier (vmcnt auto-waited at use), so lgkmcnt(0)
// alone is sufficient for the slab double-buffer protocol.
#define RELAX_BARRIER()                                        \
  do {                                                         \
    asm volatile("s_waitcnt lgkmcnt(0)" ::: "memory");         \
    __builtin_amdgcn_s_barrier();                              \
  } while (0)

// LDS slab: i-pre-reduced grid, fp16, k-PAIR records.
// gI[gj][r][0..23]: halfs [0..11] = row gk=r ch 0..11, halfs [12..23] = row
// gk=r+1 ch 0..11, r in [0,6]. Pair record 48 B, 16B-aligned; stride puts the
// 7 r-values in disjoint bank quads, gj stride 176 halfs rotates by 24 banks.
#define GPR 24
#define NPAIR (GD - 1)
#define GJS_H (NPAIR * GPR + 8)   // 176 halfs per gj
#define LDS_HALFS (GW * GJS_H)    // 2816 halfs = 5632 B

// One 48B pair record (rows r,r+1 of one gj) -> 6 half2 accumulators.
__device__ inline void accum_rec(const __half* __restrict__ buf, int off,
                                 __half2 b0, __half2 b1, __half2* __restrict__ acc) {
  union U { uint4 u; __half2 h[4]; };
  const uint4* p = reinterpret_cast<const uint4*>(buf + off);
  U qa, qb, qc;
  qa.u = p[0]; qb.u = p[1]; qc.u = p[2];
  acc[0] = __hfma2(b0, qa.h[0], acc[0]);
  acc[1] = __hfma2(b0, qa.h[1], acc[1]);
  acc[2] = __hfma2(b0, qa.h[2], acc[2]);
  acc[3] = __hfma2(b0, qa.h[3], acc[3]);
  acc[4] = __hfma2(b0, qb.h[0], acc[4]);
  acc[5] = __hfma2(b0, qb.h[1], acc[5]);
  acc[0] = __hfma2(b1, qb.h[2], acc[0]);
  acc[1] = __hfma2(b1, qb.h[3], acc[1]);
  acc[2] = __hfma2(b1, qc.h[0], acc[2]);
  acc[3] = __hfma2(b1, qc.h[1], acc[3]);
  acc[4] = __hfma2(b1, qc.h[2], acc[4]);
  acc[5] = __hfma2(b1, qc.h[3], acc[5]);
}

// i-weights for global row index i (uniform per block at each iteration).
__device__ inline void i_weights(int i, float& wi0, float& wi1, int& gi0c, int& gi1c) {
  float fi  = (i + 0.5f) * (1.0f / 64.0f) - 0.5f;
  float fif = floorf(fi);
  int   gi0 = (int)fif;
  float ti  = fi - fif;
  wi0 = 1.0f - ti; wi1 = ti;
  gi0c = gi0 < 0 ? 0 : gi0;
  gi1c = (gi0 + 1 > GH - 1) ? GH - 1 : gi0 + 1;
}

// Phase-1 staged write: slot tid<384 covers (c,k,gj-quad); v0/v1 are the two
// gi-plane float4s already in registers.
__device__ inline void slab_write(__half* __restrict__ buf, int gq, int ck,
                                  float wi0, float wi1, float4 v0, float4 v1) {
  int gk = ck & 7;
  int c  = ck >> 3;
  float vals[4] = {wi0 * v0.x + wi1 * v1.x, wi0 * v0.y + wi1 * v1.y,
                   wi0 * v0.z + wi1 * v1.z, wi0 * v0.w + wi1 * v1.w};
#pragma unroll
  for (int m = 0; m < 4; ++m) {
    __half hv = __float2half(vals[m]);
    int base = (gq * 4 + m) * GJS_H;
    if (gk < GD - 1) buf[base + gk * GPR + c] = hv;            // row-low of pair gk
    if (gk > 0)      buf[base + (gk - 1) * GPR + 12 + c] = hv; // row-high of pair gk-1
  }
}

__global__ __launch_bounds__(TPB, 4) void slice_pipe_k(const float* __restrict__ grid,
                                                       const float* __restrict__ guide,
                                                       float* __restrict__ out) {
  __shared__ __half gI[2][LDS_HALFS];

  const int tid = threadIdx.x;
  const int r0  = blockIdx.x * ROWS;     // global row id base (= b*1024 + i0)
  const int b   = r0 >> 10;              // ROWS divides 1024: b uniform
  const int j0  = tid << 1;              // 2 px per thread

  const float* gb      = grid + (size_t)b * (GC * GD * GH * GW);
  const float* guide_b = guide + ((size_t)b << 20);

  // --- j cell (constant for this thread across all rows) ---
  float fj  = (j0 + 0.5f) * (1.0f / 64.0f) - 0.5f;
  float fjf = floorf(fj);
  int   gj0 = (int)fjf;
  float tj0 = fj - fjf;
  int gj0c = gj0 < 0 ? 0 : gj0;
  int gj1c = (gj0 + 1 > GW - 1) ? GW - 1 : gj0 + 1;
  const int rj0 = gj0c * GJS_H;
  const int rj1 = gj1c * GJS_H;

  // phase-1 slot for this thread (slots 0..383)
  const bool p1 = tid < GC * GD * (GW / 4);
  const int  gq = tid & 3;
  const int  ck = tid >> 2;
  const float* rowbase = gb + (ck << 8);

  // --- prologue: stage row r0 ---
  float wi0, wi1; int gi0c, gi1c;
  i_weights(r0 & (H - 1), wi0, wi1, gi0c, gi1c);
  float4 v0 = {}, v1 = {};
  if (p1) {
    v0 = *reinterpret_cast<const float4*>(rowbase + gi0c * GW + gq * 4);
    v1 = *reinterpret_cast<const float4*>(rowbase + gi1c * GW + gq * 4);
  }
  float2 g_cur = *reinterpret_cast<const float2*>(guide_b + ((r0 & (H - 1)) << 10) + j0);
  if (p1) slab_write(gI[0], gq, ck, wi0, wi1, v0, v1);
  RELAX_BARRIER();

  int cur = 0;
#pragma unroll
  for (int r = 0; r < ROWS; ++r) {
    const int i = (r0 + r) & (H - 1);
    const bool has_next = (r + 1 < ROWS);

    // (1) issue next row's loads early — latency hides under phase 2
    float4 nv0 = {}, nv1 = {};
    float2 g_nxt = {};
    float nwi0 = 0.f, nwi1 = 0.f;
    if (has_next) {
      int i_n = (r0 + r + 1) & (H - 1);
      int ngi0c, ngi1c;
      i_weights(i_n, nwi0, nwi1, ngi0c, ngi1c);
      if (p1) {
        nv0 = *reinterpret_cast<const float4*>(rowbase + ngi0c * GW + gq * 4);
        nv1 = *reinterpret_cast<const float4*>(rowbase + ngi1c * GW + gq * 4);
      }
      g_nxt = *reinterpret_cast<const float2*>(guide_b + (i_n << 10) + j0);
    }

    // (2) phase 2: 2 pixels from slab buffer `cur`
    const __half* buf = gI[cur];
    __half2 acc[2][6];
#pragma unroll
    for (int p = 0; p < 2; ++p)
#pragma unroll
      for (int t = 0; t < 6; ++t) acc[p][t] = __float2half2_rn(0.0f);

    const float gvv[2] = {g_cur.x, g_cur.y};
#pragma unroll
    for (int p = 0; p < 2; ++p) {
      float tj  = tj0 + p * (1.0f / 64.0f);
      float wj0 = 1.0f - tj, wj1 = tj;

      // k weights: plain lerp (sqrt(tk^2+1e-8) == tk within 1e-4 for tk in
      // [0,1)); clamp folded into pair weights (pair rr covers rows rr, rr+1).
      float fk  = gvv[p] * (float)GD - 0.5f;
      float fkf = floorf(fk);
      int   gk0 = (int)fkf;                  // in [-1, 7]
      float tk  = fk - fkf;
      bool lo = gk0 < 0, hi = gk0 > GD - 2;
      int  rr = lo ? 0 : (hi ? GD - 2 : gk0);
      float a0 = lo ? 1.0f : (hi ? 0.0f : 1.0f - tk);
      float a1 = lo ? 0.0f : (hi ? 1.0f : tk);

      __half2 b00 = __float2half2_rn(wj0 * a0);
      __half2 b01 = __float2half2_rn(wj0 * a1);
      __half2 b10 = __float2half2_rn(wj1 * a0);
      __half2 b11 = __float2half2_rn(wj1 * a1);

      int off = rr * GPR;
      accum_rec(buf, rj0 + off, b00, b01, acc[p]);
      accum_rec(buf, rj1 + off, b10, b11, acc[p]);
    }

    // stores: out[b][c][i][j0..j0+1], float2 per channel
    float* ob = out + (((size_t)b * GC) << 20) + ((size_t)i << 10) + j0;
#pragma unroll
    for (int c2 = 0; c2 < 6; ++c2) {
      float2 f0 = __half22float2(acc[0][c2]);
      float2 f1 = __half22float2(acc[1][c2]);
      *reinterpret_cast<float2*>(ob + ((size_t)(2 * c2) << 20)) = make_float2(f0.x, f1.x);
      *reinterpret_cast<float2*>(ob + ((size_t)(2 * c2 + 1) << 20)) = make_float2(f0.y, f1.y);
    }

    // (3) write-late: next slab into the other buffer, then one RELAXED
    // barrier (no vmcnt drain: this iteration's stores keep flowing).
    if (has_next) {
      if (p1) slab_write(gI[cur ^ 1], gq, ck, nwi0, nwi1, nv0, nv1);
      g_cur = g_nxt;
      RELAX_BARRIER();
      cur ^= 1;
    }
  }
}

extern "C" void kernel_launch(void* const* d_in, const int* in_sizes, int n_in,
                              void* d_out, int out_size, void* d_ws, size_t ws_size,
                              hipStream_t stream) {
  const float* grid  = (const float*)d_in[0];   // (2,12,8,16,16) fp32
  const float* guide = (const float*)d_in[1];   // (2,1,1024,1024) fp32
  float* out = (float*)d_out;                   // (2,12,1024,1024) fp32

  const int nblocks = NB * H / ROWS;            // 512 blocks = 2 per CU, resident
  slice_pipe_k<<<nblocks, TPB, 0, stream>>>(grid, guide, out);
}